// Round 13
// baseline (179.909 us; speedup 1.0000x reference)
//
#include <hip/hip_runtime.h>
#include <math.h>

#define HW 16384
#define WID 128
#define BB 4
#define CC 21
#define DD 256
#define NA 84      // BB*CC anchors
#define NV 100
#define NN 8400    // NA*NV
#define NPOS 400   // BB*NV same-class columns per row
#define NPAD 8448  // 66 * 128
#define NTILE 66   // NPAD/128
#define NTRI 2211  // NTILE*(NTILE+1)/2 triangle tiles
#define NPOSBLK (16 * CC)       // 336 pos tiles
#define PXC 32     // gather pixel chunk
#define NCHUNK (BB * HW / PXC)  // 2048 dense gather blocks
#define NFILLB 84  // filler tail blocks

typedef __bf16 bf16;
typedef bf16 v8bf __attribute__((ext_vector_type(8)));
typedef bf16 v4bf __attribute__((ext_vector_type(4)));
typedef float v4f __attribute__((ext_vector_type(4)));

#define AS1(p) ((const __attribute__((address_space(1))) void*)(p))
#define AS3(p) ((__attribute__((address_space(3))) void*)(p))

// ---------------- K1: bilinear 2x upsample + argmax; init map/counter ------
__global__ void pred_kernel(const float* __restrict__ predict, int* __restrict__ pred,
                            int* __restrict__ map, int* __restrict__ fill_cnt) {
  int t = blockIdx.x * blockDim.x + threadIdx.x;   // 0..65535
  if (t == 0) *fill_cnt = 0;
  map[t] = -1;
  int b = t / HW;
  int p = t % HW;
  int y = p / WID, x = p % WID;
  float yin = y * 0.5f - 0.25f;
  float xin = x * 0.5f - 0.25f;
  int y0 = (int)floorf(yin), x0 = (int)floorf(xin);
  float fy = yin - (float)y0, fx = xin - (float)x0;
  int y0c = max(y0, 0), y1c = min(y0 + 1, 63);
  int x0c = max(x0, 0), x1c = min(x0 + 1, 63);
  float w00 = (1.f - fy) * (1.f - fx), w01 = (1.f - fy) * fx;
  float w10 = fy * (1.f - fx),        w11 = fy * fx;
  const float* pb = predict + (size_t)b * CC * 4096;
  float best = -1e30f; int bc = 0;
  for (int c = 0; c < CC; ++c) {
    const float* pc = pb + c * 4096;
    float v = w00 * pc[y0c * 64 + x0c] + w01 * pc[y0c * 64 + x1c]
            + w10 * pc[y1c * 64 + x0c] + w11 * pc[y1c * 64 + x1c];
    if (v > best) { best = v; bc = c; }  // strict > keeps first index (jnp.argmax)
  }
  pred[t] = bc;
}

// ---------------- K2: selection -> dense map + filler list -----------------
__global__ __launch_bounds__(256) void select_kernel(const int* __restrict__ pred,
                                                     const int* __restrict__ labels,
                                                     int* __restrict__ map,
                                                     int2* __restrict__ fill_list,
                                                     int* __restrict__ fill_cnt) {
  int pair = blockIdx.x;         // 0..83
  int b = pair / CC, c = pair % CC;
  int tid = threadIdx.x;         // 0..255
  const int4* pb = (const int4*)(pred + b * HW) + tid * 16;
  const int4* lb = (const int4*)(labels + b * HW) + tid * 16;

  unsigned long long hm = 0ull, em = 0ull;
  #pragma unroll
  for (int g = 0; g < 16; ++g) {
    int4 p4 = pb[g];
    int4 l4 = lb[g];
    unsigned long long h =
        ((unsigned long long)((p4.x == c) & (l4.x != c)))      |
        ((unsigned long long)((p4.y == c) & (l4.y != c)) << 1) |
        ((unsigned long long)((p4.z == c) & (l4.z != c)) << 2) |
        ((unsigned long long)((p4.w == c) & (l4.w != c)) << 3);
    unsigned long long e =
        ((unsigned long long)((p4.x == c) & (l4.x == c)))      |
        ((unsigned long long)((p4.y == c) & (l4.y == c)) << 1) |
        ((unsigned long long)((p4.z == c) & (l4.z == c)) << 2) |
        ((unsigned long long)((p4.w == c) & (l4.w == c)) << 3);
    hm |= h << (g * 4);
    em |= e << (g * 4);
  }
  int nh_t = __popcll(hm), ne_t = __popcll(em);

  __shared__ int sh[256], se[256], ss[256];
  sh[tid] = nh_t; se[tid] = ne_t;
  __syncthreads();
  for (int off = 1; off < 256; off <<= 1) {
    int vh = (tid >= off) ? sh[tid - off] : 0;
    int ve = (tid >= off) ? se[tid - off] : 0;
    __syncthreads();
    sh[tid] += vh; se[tid] += ve;
    __syncthreads();
  }
  int h_excl = sh[tid] - nh_t, e_excl = se[tid] - ne_t;
  int nh = sh[255], ne = se[255];

  const int half = NV / 2;
  int hk;
  if (nh >= half && ne >= half) hk = half;
  else if (nh >= half)          hk = NV - ne;
  else                          hk = nh;
  int ek = NV - hk;

  int takeh = min(max(hk - h_excl, 0), nh_t);
  int takee = min(max(ek - e_excl, 0), ne_t);
  int sel_t = takeh + takee;
  ss[tid] = sel_t;
  __syncthreads();
  for (int off = 1; off < 256; off <<= 1) {
    int vs = (tid >= off) ? ss[tid - off] : 0;
    __syncthreads();
    ss[tid] += vs;
    __syncthreads();
  }
  int s_excl = ss[tid] - sel_t;
  int total_sel = ss[255];
  int F = NV - total_sel;
  int u_excl = tid * 64 - s_excl;

  int sc = 0, uc = 0, hc = 0, ec = 0;
  for (int l = 0; l < 64; ++l) {
    int p = tid * 64 + l;
    int hard = (int)((hm >> l) & 1ull);
    int easy = (int)((em >> l) & 1ull);
    bool sel = (hard && hc < takeh) || (easy && ec < takee);
    hc += hard; ec += easy;
    if (sel) {
      int v = s_excl + sc;
      if (v < NV) map[b * HW + p] = v * NA + pair;
      sc++;
    } else {
      int v = total_sel + u_excl + uc;
      if (u_excl + uc < F) {
        int slot = atomicAdd(fill_cnt, 1);
        fill_list[slot] = make_int2(v * NA + pair, p);
      }
      uc++;
    }
  }
}

// ---------------- K3: DENSE gather + L2 normalize -> bf16 ------------------
// feats is read once -> NON-TEMPORAL loads (nt flag, no L2 allocation), so
// the 64 MB sweep doesn't evict cf before gemm (R12 post-mortem: gemm
// +17us from L2 pollution by this kernel).
__global__ __launch_bounds__(256) void gather_kernel(const float* __restrict__ feats,
                                                     const int* __restrict__ map,
                                                     const int2* __restrict__ fill_list,
                                                     const int* __restrict__ fill_cnt,
                                                     bf16* __restrict__ cf) {
  __shared__ float tile[PXC * 257];   // [px][d], stride 257: 32.9 KB
  __shared__ float ssp[8][PXC];
  __shared__ float inv_s[PXC];
  __shared__ int sn[PXC], sx[PXC], scnt;
  __shared__ float fred[4];
  int g = blockIdx.x;
  int t = threadIdx.x;

  if (g == NCHUNK) {                  // zero pad rows NN..NPAD-1
    v8bf z = {};
    for (int e = t; e < (NPAD - NN) * DD / 8; e += 256)
      *(v8bf*)(cf + (size_t)NN * DD + e * 8) = z;
    return;
  }
  if (g > NCHUNK) {                   // filler tail (scattered, rare)
    int cnt = *fill_cnt;
    int d = t;
    for (int e = g - NCHUNK - 1; e < cnt; e += NFILLB) {
      int2 fe = fill_list[e];
      int n = fe.x, p = fe.y;
      int b = (n % NA) / CC;
      float val = feats[((size_t)(b * DD + d)) * HW + p];
      float ss = val * val;
      for (int o = 32; o; o >>= 1) ss += __shfl_down(ss, o);
      if ((d & 63) == 0) fred[d >> 6] = ss;
      __syncthreads();
      float tot = fred[0] + fred[1] + fred[2] + fred[3];
      float inv = 1.0f / fmaxf(sqrtf(tot), 1e-12f);
      cf[(size_t)n * DD + d] = (bf16)(val * inv);
      __syncthreads();
    }
    return;
  }

  int b = g >> 9;                     // 512 chunks per image
  int p0 = (g & 511) * PXC;
  int px = t & 31, dg = t >> 5;       // dg: 0..7, 32 d's each

  const float* base = feats + ((size_t)b * DD + dg * 32) * HW + p0 + px;
  float ss = 0.f;
  #pragma unroll 8
  for (int k = 0; k < 32; ++k) {
    float v = __builtin_nontemporal_load(&base[(size_t)k * HW]);
    tile[px * 257 + dg * 32 + k] = v;
    ss += v * v;
  }
  ssp[dg][px] = ss;
  __syncthreads();
  if (t == 0) {
    int cnum = 0;
    for (int x = 0; x < PXC; ++x) {
      int n = map[b * HW + p0 + x];
      if (n >= 0) { sn[cnum] = n; sx[cnum] = x; ++cnum; }
    }
    scnt = cnum;
  }
  if (t < PXC) {
    float tot = 0.f;
    #pragma unroll
    for (int j = 0; j < 8; ++j) tot += ssp[j][t];
    inv_s[t] = 1.0f / fmaxf(sqrtf(tot), 1e-12f);
  }
  __syncthreads();

  int wv = t >> 6, ln = t & 63;
  for (int s = wv; s < scnt; s += 4) {
    int n = sn[s], x = sx[s];
    float inv = inv_s[x];
    int d0 = ln * 4;
    v4bf o;
    #pragma unroll
    for (int j = 0; j < 4; ++j)
      o[j] = (bf16)(tile[x * 257 + d0 + j] * inv);
    *(v4bf*)(cf + (size_t)n * DD + d0) = o;   // 512B/wave coalesced
  }
}

// ---------------- K4: fused symmetric MFMA bf16 GEMM (R11, unchanged) ------
__global__ __launch_bounds__(256) void gemm_kernel(const bf16* __restrict__ cf,
                                                   float* __restrict__ row_part,
                                                   float* __restrict__ s_pos) {
  __shared__ __align__(16) bf16 smem[2 * 128 * 64];   // sA | sB, 32 KB
  bf16* sA = smem;
  bf16* sB = smem + 128 * 64;
  int blk = blockIdx.x;
  bool pos = blk >= NTRI;
  int i0, j0, c = 0, I = 0, J = 0;
  bool diag = false;
  if (!pos) {
    I = (int)((sqrtf(8.0f * blk + 1.0f) - 1.0f) * 0.5f);
    while ((I + 1) * (I + 2) / 2 <= blk) ++I;
    while (I * (I + 1) / 2 > blk) --I;
    J = blk - I * (I + 1) / 2;   // J <= I
    i0 = I * 128;
    j0 = J * 128;
    diag = (I == J);
  } else {
    int pb = blk - NTRI;
    c = pb / 16;
    int bx = pb % 16;
    i0 = (bx >> 2) * 128;        // local row tile within 512
    j0 = (bx & 3) * 128;
  }
  int tid = threadIdx.x;
  int wave = tid >> 6, lane = tid & 63;
  int wi = wave >> 1, wj = wave & 1;
  int m = lane & 15, q = lane >> 4;

  v4f acc[4][4] = {};

  int lrow = lane >> 3;          // 0..7: row within 8-row DMA chunk
  int cxor = (lane & 7) ^ lrow;  // swizzled 16B-chunk index

  for (int k0 = 0; k0 < DD; k0 += 64) {
    #pragma unroll
    for (int it = 0; it < 4; ++it) {
      int row = wave * 32 + it * 8;               // wave-uniform chunk base
      int ri = i0 + row + lrow, rj = j0 + row + lrow;
      int gi, gj;
      if (!pos) { gi = ri; gj = rj; }
      else {
        gi = (ri < NPOS) ? ((ri >> 2) * NA + (ri & 3) * CC + c) : NN;
        gj = (rj < NPOS) ? ((rj >> 2) * NA + (rj & 3) * CC + c) : NN;
      }
      __builtin_amdgcn_global_load_lds(AS1(cf + (size_t)gi * DD + k0 + cxor * 8),
                                       AS3(sA + row * 64), 16, 0, 0);
      __builtin_amdgcn_global_load_lds(AS1(cf + (size_t)gj * DD + k0 + cxor * 8),
                                       AS3(sB + row * 64), 16, 0, 0);
    }
    __syncthreads();
    #pragma unroll
    for (int kk = 0; kk < 2; ++kk) {
      v8bf af[4], bfr[4];
      #pragma unroll
      for (int tt = 0; tt < 4; ++tt) {
        int r = wi * 64 + tt * 16 + m;
        af[tt] = *(const v8bf*)(sA + r * 64 + (((kk * 4 + q) ^ (m & 7)) * 8));
      }
      #pragma unroll
      for (int tt = 0; tt < 4; ++tt) {
        int r = wj * 64 + tt * 16 + m;
        bfr[tt] = *(const v8bf*)(sB + r * 64 + (((kk * 4 + q) ^ (m & 7)) * 8));
      }
      #pragma unroll
      for (int ti = 0; ti < 4; ++ti)
        #pragma unroll
        for (int tj = 0; tj < 4; ++tj)
          acc[ti][tj] = __builtin_amdgcn_mfma_f32_16x16x32_bf16(af[ti], bfr[tj], acc[ti][tj], 0, 0, 0);
    }
    __syncthreads();
  }

  // ---- epilogue: C/D layout col=lane&15, row=q*4+reg ----
  if (!pos) {
    int iw0 = i0 + wi * 64;
    int jw0 = j0 + wj * 64;
    float rowp[16];
    float colp[4] = {0.f, 0.f, 0.f, 0.f};
    #pragma unroll
    for (int tt = 0; tt < 16; ++tt) rowp[tt] = 0.f;

    #pragma unroll
    for (int ti = 0; ti < 4; ++ti) {
      #pragma unroll
      for (int r = 0; r < 4; ++r) {
        int i = iw0 + ti * 16 + q * 4 + r;
        bool iok = (i < NN);
        #pragma unroll
        for (int tj = 0; tj < 4; ++tj) {
          int j = jw0 + tj * 16 + m;
          float e = __expf(acc[ti][tj][r] * 10.0f - 10.0f);
          if (j < NN) rowp[ti * 4 + r] += e;
          if (!diag && iok) colp[tj] += e;
        }
      }
    }

    // cross-lane reduce via LDS (smem reusable after final K-barrier)
    float* redR = (float*)smem;              // [128][33] = 16.9 KB
    float* redC = (float*)smem + 128 * 33;   // [128][9]  =  4.6 KB
    #pragma unroll
    for (int ti = 0; ti < 4; ++ti)
      #pragma unroll
      for (int r = 0; r < 4; ++r) {
        int rg = wi * 64 + ti * 16 + q * 4 + r;
        redR[rg * 33 + wj * 16 + m] = rowp[ti * 4 + r];
      }
    if (!diag) {
      #pragma unroll
      for (int tj = 0; tj < 4; ++tj) {
        int cg = wj * 64 + tj * 16 + m;
        redC[cg * 9 + wi * 4 + q] = colp[tj];
      }
    }
    __syncthreads();
    if (tid < 128) {
      float s = 0.f;
      #pragma unroll
      for (int t = 0; t < 32; ++t) s += redR[tid * 33 + t];
      row_part[(size_t)J * NPAD + i0 + tid] = s;       // coalesced, once
      if (!diag) {
        float s2 = 0.f;
        #pragma unroll
        for (int t = 0; t < 8; ++t) s2 += redC[tid * 9 + t];
        row_part[(size_t)I * NPAD + j0 + tid] = s2;    // coalesced, once
      }
    }
  } else {
    #pragma unroll
    for (int ti = 0; ti < 4; ++ti) {
      #pragma unroll
      for (int r = 0; r < 4; ++r) {
        int ri = i0 + wi * 64 + ti * 16 + q * 4 + r;
        if (ri >= NPOS) continue;
        int gi = (ri >> 2) * NA + (ri & 3) * CC + c;
        #pragma unroll
        for (int tj = 0; tj < 4; ++tj) {
          int rj = j0 + wj * 64 + tj * 16 + m;
          if (rj < NPOS)
            s_pos[(size_t)gi * NPOS + rj] = acc[ti][tj][r] * 10.0f - 10.0f;
        }
      }
    }
  }
}

// ---------------- K5: loss — one wave per row ------------------------------
__global__ __launch_bounds__(256) void loss_kernel(const float* __restrict__ s_pos,
                                                   const float* __restrict__ row_part,
                                                   double* __restrict__ partials) {
  int tid = threadIdx.x;
  int wave = tid >> 6, lane = tid & 63;
  int i = blockIdx.x * 4 + wave;   // 0..8399
  const float* row = s_pos + (size_t)i * NPOS;

  float nsum = 0.f;
  for (int jb = lane; jb < NTILE; jb += 64)
    nsum += row_part[(size_t)jb * NPAD + i];

  float sp[7], ev[7];
  float psum = 0.f;
  #pragma unroll
  for (int t = 0; t < 7; ++t) {
    int k = lane + t * 64;
    if (k < NPOS) {
      sp[t] = row[k];
      ev[t] = __expf(sp[t]);
      psum += ev[t];
    } else { sp[t] = 0.f; ev[t] = 0.f; }
  }
  float comb = nsum - psum;
  for (int o = 32; o; o >>= 1) comb += __shfl_xor(comb, o);
  float ns = comb;               // full-row neg sum (butterfly = all-reduce)

  int self = (i / NA) * 4 + ((i % NA) / CC);
  float tsum = 0.f;
  #pragma unroll
  for (int t = 0; t < 7; ++t) {
    int k = lane + t * 64;
    if (k < NPOS && k != self)
      tsum += sp[t] - __logf(ev[t] + ns);
  }
  for (int o = 32; o; o >>= 1) tsum += __shfl_xor(tsum, o);

  __shared__ float r2[4];
  if (lane == 0) r2[wave] = tsum;
  __syncthreads();
  if (tid == 0) partials[blockIdx.x] = (double)(r2[0] + r2[1] + r2[2] + r2[3]);
}

__global__ void final_kernel(const double* __restrict__ partials, float* __restrict__ out) {
  int lane = threadIdx.x;        // 64
  double s = 0.0;
  for (int t = lane; t < 2100; t += 64) s += partials[t];
  for (int o = 32; o; o >>= 1) s += __shfl_down(s, o);
  if (lane == 0) out[0] = (float)(-s / 399.0 / 8400.0);
}

// ---------------- launch ---------------------------------------------------
extern "C" void kernel_launch(void* const* d_in, const int* in_sizes, int n_in,
                              void* d_out, int out_size, void* d_ws, size_t ws_size,
                              hipStream_t stream) {
  const float* feats   = (const float*)d_in[0];
  const float* predict = (const float*)d_in[1];
  const int*   labels  = (const int*)d_in[2];
  float* out = (float*)d_out;
  char* ws = (char*)d_ws;

  // workspace layout (bytes) — all buffers 4096-aligned (cf especially:
  // unaligned base made every 128B staging DMA straddle an extra line)
  int*    pred      = (int*)(ws + 0);           //   262144
  int*    map       = (int*)(ws + 262144);      //   262144
  int*    fill_cnt  = (int*)(ws + 524288);      //     4096
  int2*   fill_list = (int2*)(ws + 528384);     //    69632
  float*  row_part  = (float*)(ws + 598016);    //  2232320 (66*8448*4 pad)
  double* partials  = (double*)(ws + 2830336);  //    20480
  bf16*   cf        = (bf16*)(ws + 2850816);    //  4325376 (NPAD*256*2)
  float*  s_pos     = (float*)(ws + 7176192);   // 13440000 (end ~20.6 MB)

  pred_kernel<<<256, 256, 0, stream>>>(predict, pred, map, fill_cnt);
  select_kernel<<<NA, 256, 0, stream>>>(pred, labels, map, fill_list, fill_cnt);
  gather_kernel<<<NCHUNK + 1 + NFILLB, 256, 0, stream>>>(feats, map, fill_list, fill_cnt, cf);
  gemm_kernel<<<NTRI + NPOSBLK, 256, 0, stream>>>(cf, row_part, s_pos);
  loss_kernel<<<2100, 256, 0, stream>>>(s_pos, row_part, partials);
  final_kernel<<<1, 64, 0, stream>>>(partials, out);
}

// Round 14
// 171.500 us; speedup vs baseline: 1.0490x; 1.0490x over previous
//
#include <hip/hip_runtime.h>
#include <math.h>

#define HW 16384
#define WID 128
#define BB 4
#define CC 21
#define DD 256
#define NA 84      // BB*CC anchors
#define NV 100
#define NN 8400    // NA*NV
#define NPOS 400   // BB*NV same-class columns per row
#define NPAD 8448  // 66 * 128
#define NTILE 66   // NPAD/128
#define NTRI 2211  // NTILE*(NTILE+1)/2 triangle tiles
#define NPOSBLK (16 * CC)       // 336 pos tiles
#define PXC 32     // gather pixel chunk
#define NCHUNK (BB * HW / PXC)  // 2048 dense gather blocks
#define NFILLB 84  // filler tail blocks

typedef __bf16 bf16;
typedef bf16 v8bf __attribute__((ext_vector_type(8)));
typedef bf16 v4bf __attribute__((ext_vector_type(4)));
typedef float v4f __attribute__((ext_vector_type(4)));

#define AS1(p) ((const __attribute__((address_space(1))) void*)(p))
#define AS3(p) ((__attribute__((address_space(3))) void*)(p))

// ---------------- K1: bilinear 2x upsample + argmax; init map/counter ------
__global__ void pred_kernel(const float* __restrict__ predict, int* __restrict__ pred,
                            int* __restrict__ map, int* __restrict__ fill_cnt) {
  int t = blockIdx.x * blockDim.x + threadIdx.x;   // 0..65535
  if (t == 0) *fill_cnt = 0;
  map[t] = -1;
  int b = t / HW;
  int p = t % HW;
  int y = p / WID, x = p % WID;
  float yin = y * 0.5f - 0.25f;
  float xin = x * 0.5f - 0.25f;
  int y0 = (int)floorf(yin), x0 = (int)floorf(xin);
  float fy = yin - (float)y0, fx = xin - (float)x0;
  int y0c = max(y0, 0), y1c = min(y0 + 1, 63);
  int x0c = max(x0, 0), x1c = min(x0 + 1, 63);
  float w00 = (1.f - fy) * (1.f - fx), w01 = (1.f - fy) * fx;
  float w10 = fy * (1.f - fx),        w11 = fy * fx;
  const float* pb = predict + (size_t)b * CC * 4096;
  float best = -1e30f; int bc = 0;
  for (int c = 0; c < CC; ++c) {
    const float* pc = pb + c * 4096;
    float v = w00 * pc[y0c * 64 + x0c] + w01 * pc[y0c * 64 + x1c]
            + w10 * pc[y1c * 64 + x0c] + w11 * pc[y1c * 64 + x1c];
    if (v > best) { best = v; bc = c; }  // strict > keeps first index (jnp.argmax)
  }
  pred[t] = bc;
}

// ---------------- K2: selection -> dense map + filler list -----------------
__global__ __launch_bounds__(256) void select_kernel(const int* __restrict__ pred,
                                                     const int* __restrict__ labels,
                                                     int* __restrict__ map,
                                                     int2* __restrict__ fill_list,
                                                     int* __restrict__ fill_cnt) {
  int pair = blockIdx.x;         // 0..83
  int b = pair / CC, c = pair % CC;
  int tid = threadIdx.x;         // 0..255
  const int4* pb = (const int4*)(pred + b * HW) + tid * 16;
  const int4* lb = (const int4*)(labels + b * HW) + tid * 16;

  unsigned long long hm = 0ull, em = 0ull;
  #pragma unroll
  for (int g = 0; g < 16; ++g) {
    int4 p4 = pb[g];
    int4 l4 = lb[g];
    unsigned long long h =
        ((unsigned long long)((p4.x == c) & (l4.x != c)))      |
        ((unsigned long long)((p4.y == c) & (l4.y != c)) << 1) |
        ((unsigned long long)((p4.z == c) & (l4.z != c)) << 2) |
        ((unsigned long long)((p4.w == c) & (l4.w != c)) << 3);
    unsigned long long e =
        ((unsigned long long)((p4.x == c) & (l4.x == c)))      |
        ((unsigned long long)((p4.y == c) & (l4.y == c)) << 1) |
        ((unsigned long long)((p4.z == c) & (l4.z == c)) << 2) |
        ((unsigned long long)((p4.w == c) & (l4.w == c)) << 3);
    hm |= h << (g * 4);
    em |= e << (g * 4);
  }
  int nh_t = __popcll(hm), ne_t = __popcll(em);

  __shared__ int sh[256], se[256], ss[256];
  sh[tid] = nh_t; se[tid] = ne_t;
  __syncthreads();
  for (int off = 1; off < 256; off <<= 1) {
    int vh = (tid >= off) ? sh[tid - off] : 0;
    int ve = (tid >= off) ? se[tid - off] : 0;
    __syncthreads();
    sh[tid] += vh; se[tid] += ve;
    __syncthreads();
  }
  int h_excl = sh[tid] - nh_t, e_excl = se[tid] - ne_t;
  int nh = sh[255], ne = se[255];

  const int half = NV / 2;
  int hk;
  if (nh >= half && ne >= half) hk = half;
  else if (nh >= half)          hk = NV - ne;
  else                          hk = nh;
  int ek = NV - hk;

  int takeh = min(max(hk - h_excl, 0), nh_t);
  int takee = min(max(ek - e_excl, 0), ne_t);
  int sel_t = takeh + takee;
  ss[tid] = sel_t;
  __syncthreads();
  for (int off = 1; off < 256; off <<= 1) {
    int vs = (tid >= off) ? ss[tid - off] : 0;
    __syncthreads();
    ss[tid] += vs;
    __syncthreads();
  }
  int s_excl = ss[tid] - sel_t;
  int total_sel = ss[255];
  int F = NV - total_sel;
  int u_excl = tid * 64 - s_excl;

  int sc = 0, uc = 0, hc = 0, ec = 0;
  for (int l = 0; l < 64; ++l) {
    int p = tid * 64 + l;
    int hard = (int)((hm >> l) & 1ull);
    int easy = (int)((em >> l) & 1ull);
    bool sel = (hard && hc < takeh) || (easy && ec < takee);
    hc += hard; ec += easy;
    if (sel) {
      int v = s_excl + sc;
      if (v < NV) map[b * HW + p] = v * NA + pair;
      sc++;
    } else {
      int v = total_sel + u_excl + uc;
      if (u_excl + uc < F) {
        int slot = atomicAdd(fill_cnt, 1);
        fill_list[slot] = make_int2(v * NA + pair, p);
      }
      uc++;
    }
  }
}

// ---------------- K3: DENSE gather + L2 normalize -> bf16 ------------------
// R13 post-mortem: NT loads cost gather ~24us (feats is L3-resident via the
// harness restore; NT demoted those hits). Reverted to plain loads; all 32
// per-thread loads batched into registers first for max MLP. 4096-aligned
// cf retained (R13's gemm fix candidate).
__global__ __launch_bounds__(256) void gather_kernel(const float* __restrict__ feats,
                                                     const int* __restrict__ map,
                                                     const int2* __restrict__ fill_list,
                                                     const int* __restrict__ fill_cnt,
                                                     bf16* __restrict__ cf) {
  __shared__ float tile[PXC * 257];   // [px][d], stride 257: 32.9 KB
  __shared__ float ssp[8][PXC];
  __shared__ float inv_s[PXC];
  __shared__ int sn[PXC], sx[PXC], scnt;
  __shared__ float fred[4];
  int g = blockIdx.x;
  int t = threadIdx.x;

  if (g == NCHUNK) {                  // zero pad rows NN..NPAD-1
    v8bf z = {};
    for (int e = t; e < (NPAD - NN) * DD / 8; e += 256)
      *(v8bf*)(cf + (size_t)NN * DD + e * 8) = z;
    return;
  }
  if (g > NCHUNK) {                   // filler tail (scattered, rare)
    int cnt = *fill_cnt;
    int d = t;
    for (int e = g - NCHUNK - 1; e < cnt; e += NFILLB) {
      int2 fe = fill_list[e];
      int n = fe.x, p = fe.y;
      int b = (n % NA) / CC;
      float val = feats[((size_t)(b * DD + d)) * HW + p];
      float ss = val * val;
      for (int o = 32; o; o >>= 1) ss += __shfl_down(ss, o);
      if ((d & 63) == 0) fred[d >> 6] = ss;
      __syncthreads();
      float tot = fred[0] + fred[1] + fred[2] + fred[3];
      float inv = 1.0f / fmaxf(sqrtf(tot), 1e-12f);
      cf[(size_t)n * DD + d] = (bf16)(val * inv);
      __syncthreads();
    }
    return;
  }

  int b = g >> 9;                     // 512 chunks per image
  int p0 = (g & 511) * PXC;
  int px = t & 31, dg = t >> 5;       // dg: 0..7, 32 d's each

  const float* base = feats + ((size_t)b * DD + dg * 32) * HW + p0 + px;
  float v[32];
  #pragma unroll
  for (int k = 0; k < 32; ++k)        // batch all loads first -> full MLP
    v[k] = base[(size_t)k * HW];
  float ss = 0.f;
  #pragma unroll
  for (int k = 0; k < 32; ++k) {
    tile[px * 257 + dg * 32 + k] = v[k];
    ss += v[k] * v[k];
  }
  ssp[dg][px] = ss;
  __syncthreads();
  if (t == 0) {
    int cnum = 0;
    for (int x = 0; x < PXC; ++x) {
      int n = map[b * HW + p0 + x];
      if (n >= 0) { sn[cnum] = n; sx[cnum] = x; ++cnum; }
    }
    scnt = cnum;
  }
  if (t < PXC) {
    float tot = 0.f;
    #pragma unroll
    for (int j = 0; j < 8; ++j) tot += ssp[j][t];
    inv_s[t] = 1.0f / fmaxf(sqrtf(tot), 1e-12f);
  }
  __syncthreads();

  int wv = t >> 6, ln = t & 63;
  for (int s = wv; s < scnt; s += 4) {
    int n = sn[s], x = sx[s];
    float inv = inv_s[x];
    int d0 = ln * 4;
    v4bf o;
    #pragma unroll
    for (int j = 0; j < 4; ++j)
      o[j] = (bf16)(tile[x * 257 + d0 + j] * inv);
    *(v4bf*)(cf + (size_t)n * DD + d0) = o;   // 512B/wave coalesced
  }
}

// ---------------- K4: fused symmetric MFMA bf16 GEMM (R11, unchanged) ------
__global__ __launch_bounds__(256) void gemm_kernel(const bf16* __restrict__ cf,
                                                   float* __restrict__ row_part,
                                                   float* __restrict__ s_pos) {
  __shared__ __align__(16) bf16 smem[2 * 128 * 64];   // sA | sB, 32 KB
  bf16* sA = smem;
  bf16* sB = smem + 128 * 64;
  int blk = blockIdx.x;
  bool pos = blk >= NTRI;
  int i0, j0, c = 0, I = 0, J = 0;
  bool diag = false;
  if (!pos) {
    I = (int)((sqrtf(8.0f * blk + 1.0f) - 1.0f) * 0.5f);
    while ((I + 1) * (I + 2) / 2 <= blk) ++I;
    while (I * (I + 1) / 2 > blk) --I;
    J = blk - I * (I + 1) / 2;   // J <= I
    i0 = I * 128;
    j0 = J * 128;
    diag = (I == J);
  } else {
    int pb = blk - NTRI;
    c = pb / 16;
    int bx = pb % 16;
    i0 = (bx >> 2) * 128;        // local row tile within 512
    j0 = (bx & 3) * 128;
  }
  int tid = threadIdx.x;
  int wave = tid >> 6, lane = tid & 63;
  int wi = wave >> 1, wj = wave & 1;
  int m = lane & 15, q = lane >> 4;

  v4f acc[4][4] = {};

  int lrow = lane >> 3;          // 0..7: row within 8-row DMA chunk
  int cxor = (lane & 7) ^ lrow;  // swizzled 16B-chunk index

  for (int k0 = 0; k0 < DD; k0 += 64) {
    #pragma unroll
    for (int it = 0; it < 4; ++it) {
      int row = wave * 32 + it * 8;               // wave-uniform chunk base
      int ri = i0 + row + lrow, rj = j0 + row + lrow;
      int gi, gj;
      if (!pos) { gi = ri; gj = rj; }
      else {
        gi = (ri < NPOS) ? ((ri >> 2) * NA + (ri & 3) * CC + c) : NN;
        gj = (rj < NPOS) ? ((rj >> 2) * NA + (rj & 3) * CC + c) : NN;
      }
      __builtin_amdgcn_global_load_lds(AS1(cf + (size_t)gi * DD + k0 + cxor * 8),
                                       AS3(sA + row * 64), 16, 0, 0);
      __builtin_amdgcn_global_load_lds(AS1(cf + (size_t)gj * DD + k0 + cxor * 8),
                                       AS3(sB + row * 64), 16, 0, 0);
    }
    __syncthreads();
    #pragma unroll
    for (int kk = 0; kk < 2; ++kk) {
      v8bf af[4], bfr[4];
      #pragma unroll
      for (int tt = 0; tt < 4; ++tt) {
        int r = wi * 64 + tt * 16 + m;
        af[tt] = *(const v8bf*)(sA + r * 64 + (((kk * 4 + q) ^ (m & 7)) * 8));
      }
      #pragma unroll
      for (int tt = 0; tt < 4; ++tt) {
        int r = wj * 64 + tt * 16 + m;
        bfr[tt] = *(const v8bf*)(sB + r * 64 + (((kk * 4 + q) ^ (m & 7)) * 8));
      }
      #pragma unroll
      for (int ti = 0; ti < 4; ++ti)
        #pragma unroll
        for (int tj = 0; tj < 4; ++tj)
          acc[ti][tj] = __builtin_amdgcn_mfma_f32_16x16x32_bf16(af[ti], bfr[tj], acc[ti][tj], 0, 0, 0);
    }
    __syncthreads();
  }

  // ---- epilogue: C/D layout col=lane&15, row=q*4+reg ----
  if (!pos) {
    int iw0 = i0 + wi * 64;
    int jw0 = j0 + wj * 64;
    float rowp[16];
    float colp[4] = {0.f, 0.f, 0.f, 0.f};
    #pragma unroll
    for (int tt = 0; tt < 16; ++tt) rowp[tt] = 0.f;

    #pragma unroll
    for (int ti = 0; ti < 4; ++ti) {
      #pragma unroll
      for (int r = 0; r < 4; ++r) {
        int i = iw0 + ti * 16 + q * 4 + r;
        bool iok = (i < NN);
        #pragma unroll
        for (int tj = 0; tj < 4; ++tj) {
          int j = jw0 + tj * 16 + m;
          float e = __expf(acc[ti][tj][r] * 10.0f - 10.0f);
          if (j < NN) rowp[ti * 4 + r] += e;
          if (!diag && iok) colp[tj] += e;
        }
      }
    }

    // cross-lane reduce via LDS (smem reusable after final K-barrier)
    float* redR = (float*)smem;              // [128][33] = 16.9 KB
    float* redC = (float*)smem + 128 * 33;   // [128][9]  =  4.6 KB
    #pragma unroll
    for (int ti = 0; ti < 4; ++ti)
      #pragma unroll
      for (int r = 0; r < 4; ++r) {
        int rg = wi * 64 + ti * 16 + q * 4 + r;
        redR[rg * 33 + wj * 16 + m] = rowp[ti * 4 + r];
      }
    if (!diag) {
      #pragma unroll
      for (int tj = 0; tj < 4; ++tj) {
        int cg = wj * 64 + tj * 16 + m;
        redC[cg * 9 + wi * 4 + q] = colp[tj];
      }
    }
    __syncthreads();
    if (tid < 128) {
      float s = 0.f;
      #pragma unroll
      for (int t = 0; t < 32; ++t) s += redR[tid * 33 + t];
      row_part[(size_t)J * NPAD + i0 + tid] = s;       // coalesced, once
      if (!diag) {
        float s2 = 0.f;
        #pragma unroll
        for (int t = 0; t < 8; ++t) s2 += redC[tid * 9 + t];
        row_part[(size_t)I * NPAD + j0 + tid] = s2;    // coalesced, once
      }
    }
  } else {
    #pragma unroll
    for (int ti = 0; ti < 4; ++ti) {
      #pragma unroll
      for (int r = 0; r < 4; ++r) {
        int ri = i0 + wi * 64 + ti * 16 + q * 4 + r;
        if (ri >= NPOS) continue;
        int gi = (ri >> 2) * NA + (ri & 3) * CC + c;
        #pragma unroll
        for (int tj = 0; tj < 4; ++tj) {
          int rj = j0 + wj * 64 + tj * 16 + m;
          if (rj < NPOS)
            s_pos[(size_t)gi * NPOS + rj] = acc[ti][tj][r] * 10.0f - 10.0f;
        }
      }
    }
  }
}

// ---------------- K5: loss — one wave per row ------------------------------
__global__ __launch_bounds__(256) void loss_kernel(const float* __restrict__ s_pos,
                                                   const float* __restrict__ row_part,
                                                   double* __restrict__ partials) {
  int tid = threadIdx.x;
  int wave = tid >> 6, lane = tid & 63;
  int i = blockIdx.x * 4 + wave;   // 0..8399
  const float* row = s_pos + (size_t)i * NPOS;

  float nsum = 0.f;
  for (int jb = lane; jb < NTILE; jb += 64)
    nsum += row_part[(size_t)jb * NPAD + i];

  float sp[7], ev[7];
  float psum = 0.f;
  #pragma unroll
  for (int t = 0; t < 7; ++t) {
    int k = lane + t * 64;
    if (k < NPOS) {
      sp[t] = row[k];
      ev[t] = __expf(sp[t]);
      psum += ev[t];
    } else { sp[t] = 0.f; ev[t] = 0.f; }
  }
  float comb = nsum - psum;
  for (int o = 32; o; o >>= 1) comb += __shfl_xor(comb, o);
  float ns = comb;               // full-row neg sum (butterfly = all-reduce)

  int self = (i / NA) * 4 + ((i % NA) / CC);
  float tsum = 0.f;
  #pragma unroll
  for (int t = 0; t < 7; ++t) {
    int k = lane + t * 64;
    if (k < NPOS && k != self)
      tsum += sp[t] - __logf(ev[t] + ns);
  }
  for (int o = 32; o; o >>= 1) tsum += __shfl_xor(tsum, o);

  __shared__ float r2[4];
  if (lane == 0) r2[wave] = tsum;
  __syncthreads();
  if (tid == 0) partials[blockIdx.x] = (double)(r2[0] + r2[1] + r2[2] + r2[3]);
}

__global__ void final_kernel(const double* __restrict__ partials, float* __restrict__ out) {
  int lane = threadIdx.x;        // 64
  double s = 0.0;
  for (int t = lane; t < 2100; t += 64) s += partials[t];
  for (int o = 32; o; o >>= 1) s += __shfl_down(s, o);
  if (lane == 0) out[0] = (float)(-s / 399.0 / 8400.0);
}

// ---------------- launch ---------------------------------------------------
extern "C" void kernel_launch(void* const* d_in, const int* in_sizes, int n_in,
                              void* d_out, int out_size, void* d_ws, size_t ws_size,
                              hipStream_t stream) {
  const float* feats   = (const float*)d_in[0];
  const float* predict = (const float*)d_in[1];
  const int*   labels  = (const int*)d_in[2];
  float* out = (float*)d_out;
  char* ws = (char*)d_ws;

  // workspace layout (bytes) — all buffers 4096-aligned (cf especially:
  // unaligned base made every 128B staging DMA straddle an extra line)
  int*    pred      = (int*)(ws + 0);           //   262144
  int*    map       = (int*)(ws + 262144);      //   262144
  int*    fill_cnt  = (int*)(ws + 524288);      //     4096
  int2*   fill_list = (int2*)(ws + 528384);     //    69632
  float*  row_part  = (float*)(ws + 598016);    //  2232320 (66*8448*4 pad)
  double* partials  = (double*)(ws + 2830336);  //    20480
  bf16*   cf        = (bf16*)(ws + 2850816);    //  4325376 (NPAD*256*2)
  float*  s_pos     = (float*)(ws + 7176192);   // 13440000 (end ~20.6 MB)

  pred_kernel<<<256, 256, 0, stream>>>(predict, pred, map, fill_cnt);
  select_kernel<<<NA, 256, 0, stream>>>(pred, labels, map, fill_list, fill_cnt);
  gather_kernel<<<NCHUNK + 1 + NFILLB, 256, 0, stream>>>(feats, map, fill_list, fill_cnt, cf);
  gemm_kernel<<<NTRI + NPOSBLK, 256, 0, stream>>>(cf, row_part, s_pos);
  loss_kernel<<<2100, 256, 0, stream>>>(s_pos, row_part, partials);
  final_kernel<<<1, 64, 0, stream>>>(partials, out);
}